// Round 18
// baseline (62.132 us; speedup 1.0000x reference)
//
#include <hip/hip_runtime.h>
#include <hip/hip_bf16.h>
#include <math.h>

#define B 32
#define S 8
#define FEA 2560
#define T 800
#define NCL 512
#define EMB 256
#define H 8

#define TPB 10           // f-tiles (16 features) per block
#define XROWB 1600       // bytes per x/mask row in LDS (800 bf16, stride 1600: banks ok w/ XOR)

typedef __attribute__((ext_vector_type(8))) short bf16x8;
typedef __attribute__((ext_vector_type(4))) float f32x4;

__device__ __forceinline__ short4 cvt_bf16x4(float4 v) {
    union { short4 s4; __hip_bfloat162 h[2]; } u;
    u.h[0] = __float22bfloat162_rn(make_float2(v.x, v.y));
    u.h[1] = __float22bfloat162_rn(make_float2(v.z, v.w));
    return u.s4;
}

// One tile = 16 rows x 800 floats = 3200 float4, CONTIGUOUS in memory.
// 13 iterations x 256 threads x 16B = linear 4KB-per-instruction scan.
#define LOAD_T(t) {                                                                 \
    const float4* p_ = xb4 + (size_t)(tile0 + (t)) * 3200;                          \
    _Pragma("unroll")                                                               \
    for (int i = 0; i < 13; ++i) {                                                  \
        const int v = i * 256 + tid;                                                \
        if (v < 3200) R[i] = p_[v];                                                 \
    }                                                                               \
}

#define WRITE_T(bufsel) {                                                           \
    char* dst_ = (char*)xl[bufsel];                                                 \
    _Pragma("unroll")                                                               \
    for (int i = 0; i < 13; ++i) {                                                  \
        const int v = i * 256 + tid;                                                \
        if (v < 3200) {                                                             \
            const int row_ = v / 200, c4_ = v - row_ * 200;                         \
            *(short4*)(dst_ + row_ * XROWB + ((c4_ * 8) ^ ((row_ & 7) << 4)))       \
                = cvt_bf16x4(R[i]);                                                 \
        }                                                                           \
    }                                                                               \
}

// ---------------- Kernel A: pooled via MFMA; full-K tiles, pure linear x scan ----------------
// grid (16, 32) = 512 blocks = exactly 2/CU. Each block: 10 tiles = 512KB linear region.
__global__ __launch_bounds__(256) void pool_kernel(const float* __restrict__ x,
                                                   const float* __restrict__ mask,
                                                   float* __restrict__ pooled) {
    const int b = blockIdx.y, fg = blockIdx.x;

    __shared__ short mask_l[S * (XROWB / 2)];     // 12800 B
    __shared__ short xl[2][16 * (XROWB / 2)];     // 2 x 25600 B  (total 64000 B)

    const int tid = threadIdx.x;
    const float4* xb4 = (const float4*)(x + (size_t)b * FEA * T);
    const int tile0 = fg * TPB;

    float4 R[13];

    // ---- prologue: issue tile-0 loads; stage mask while they fly ----
    LOAD_T(0)

    for (int v = tid; v < S * 200; v += 256) {
        const int s = v / 200, c4 = v % 200;
        const float4 mv = *(const float4*)(mask + ((size_t)(b * S + s)) * T + c4 * 4);
        *(short4*)((char*)mask_l + s * XROWB + ((c4 * 8) ^ (s << 4))) = cvt_bf16x4(mv);
    }

    WRITE_T(0)               // tile 0 -> buf0 (vmcnt waits R)
    LOAD_T(1)                // tile 1 in flight
    __syncthreads();

    const int lane = tid & 63, wave = tid >> 6;
    const int kb16 = (lane >> 4) * 16;
    const int xrow = lane & 15;
    const int xswz = (xrow & 7) << 4;
    const int srow = lane & 7;
    const int mbase = srow * XROWB;
    const int mswz = srow << 4;

    // ---- main loop: 1 barrier/tile; write lags its load by a full iteration ----
    #pragma unroll 1
    for (int t = 0; t < TPB; ++t) {
        if (t < TPB - 1) WRITE_T((t + 1) & 1)     // R = tile t+1 -> other buffer
        if (t < TPB - 2) LOAD_T(t + 2)            // issue tile t+2 (drained next iter)
        if (wave == 0) {
            // full K = 800 in 25 MFMA steps; no tail
            f32x4 acc = {0.f, 0.f, 0.f, 0.f};
            const char* xbuf = (const char*)xl[t & 1];
            #pragma unroll
            for (int st = 0; st < 25; ++st) {
                const bf16x8 bx = *(const bf16x8*)(xbuf + xrow * XROWB
                                      + ((st * 64 + kb16) ^ xswz));
                const bf16x8 am = *(const bf16x8*)((const char*)mask_l + mbase
                                      + ((st * 64 + kb16) ^ mswz));
                acc = __builtin_amdgcn_mfma_f32_16x16x32_bf16(am, bx, acc, 0, 0, 0);
            }
            // C/D: col = lane&15, row = (lane>>4)*4 + i; rows 0..7 = speakers.
            if (lane < 32) {
                const int col = lane & 15;
                const int f0 = (tile0 + t) * 16;
                #pragma unroll
                for (int i = 0; i < 4; ++i) {
                    const int sr = (lane >> 4) * 4 + i;
                    pooled[(size_t)(b * S + sr) * FEA + f0 + col] = acc[i];
                }
            }
        }
        __syncthreads();     // compute(t) done; buf[t&1] free for tile t+2 next iter
    }
}

// ---------------- Kernel B1: per (b,s) denom + w, float4 + shfl-reduce (+ u, + zero out) ----------------
__global__ __launch_bounds__(256) void wden_kernel(const float* __restrict__ pooled,
                                                   const float* __restrict__ mask,
                                                   const float* __restrict__ W_w,
                                                   const float* __restrict__ W_b,
                                                   const float* __restrict__ U_w,
                                                   const float* __restrict__ U_b,
                                                   const float* __restrict__ m,
                                                   float* __restrict__ w_out,
                                                   float* __restrict__ u_out,
                                                   float* __restrict__ out) {
    __shared__ float dred[4];
    __shared__ float wred[4][8];
    const int bs  = blockIdx.x;
    const int tid = threadIdx.x;
    const int lane = tid & 63, wave = tid >> 6;

    out[bs * EMB + tid] = 0.f;   // zero for egemv atomics

    // ---- u: clusters 2bs, 2bs+1 (16 dot-256s; 16-lane groups) ----
    {
        const int job = tid >> 4, sub = tid & 15;
        const int cl  = 2 * bs + (job >> 3), h = job & 7;
        float pu = 0.f;
        #pragma unroll 4
        for (int e = sub; e < EMB; e += 16)
            pu += m[cl * EMB + e] * U_w[h * EMB + e];
        #pragma unroll
        for (int off = 8; off > 0; off >>= 1) pu += __shfl_xor(pu, off, 64);
        if (sub == 0) u_out[cl * H + h] = pu + U_b[h];
    }

    // ---- denom: float4 mask loads + wave shfl reduce (1 barrier) ----
    const float4* mk4 = (const float4*)(mask + (size_t)bs * T);   // 200 float4
    float p = 0.f;
    if (tid < 200) {
        const float4 v = mk4[tid];
        p = v.x + v.y + v.z + v.w;
    }
    #pragma unroll
    for (int off = 32; off > 0; off >>= 1) p += __shfl_xor(p, off, 64);
    if (lane == 0) dred[wave] = p;
    __syncthreads();
    const float inv_d = 1.f / (dred[0] + dred[1] + dred[2] + dred[3] + 1e-10f);

    // ---- w[h]: float4 pooled & W_w loads ----
    const float4* p4 = (const float4*)(pooled + (size_t)bs * FEA);
    const float4* W4 = (const float4*)W_w;
    float acc[8];
    #pragma unroll
    for (int h = 0; h < 8; ++h) acc[h] = 0.f;
    #pragma unroll 1
    for (int i = tid; i < FEA / 4; i += 256) {
        float4 xv = p4[i];
        xv.x *= inv_d; xv.y *= inv_d; xv.z *= inv_d; xv.w *= inv_d;
        #pragma unroll
        for (int h = 0; h < 8; ++h) {
            const float4 wv = W4[h * (FEA / 4) + i];
            acc[h] += xv.x * wv.x + xv.y * wv.y + xv.z * wv.z + xv.w * wv.w;
        }
    }
    #pragma unroll
    for (int h = 0; h < 8; ++h) {
        float v = acc[h];
        #pragma unroll
        for (int off = 32; off > 0; off >>= 1) v += __shfl_xor(v, off, 64);
        if (lane == 0) wred[wave][h] = v;
    }
    __syncthreads();
    if (tid < 8)
        w_out[bs * H + tid] = wred[0][tid] + wred[1][tid] + wred[2][tid] + wred[3][tid] + W_b[tid];
}

// ---------------- Kernel B2: fused gate + e = a @ m, n-split x4 ----------------
__global__ __launch_bounds__(256) void egemv_kernel(const float* __restrict__ w_buf,
                                                    const float* __restrict__ u_buf,
                                                    const float* __restrict__ v_w,
                                                    const float* __restrict__ v_b,
                                                    const float* __restrict__ m,
                                                    float* __restrict__ out) {
    __shared__ float a_sh[128];
    const int bs = blockIdx.x >> 2, q = blockIdx.x & 3;
    const int tid = threadIdx.x;
    const int n0 = q * 128;

    if (tid < 128) {
        const int n = n0 + tid;
        float c = v_b[0];
        #pragma unroll
        for (int h = 0; h < 8; ++h)
            c += tanhf(w_buf[bs * H + h] + u_buf[n * H + h]) * v_w[h];
        a_sh[tid] = 1.f / (1.f + expf(-c));
    }
    __syncthreads();

    float acc = 0.f;
    #pragma unroll 8
    for (int j = 0; j < 128; ++j)
        acc += a_sh[j] * m[(n0 + j) * EMB + tid];
    atomicAdd(&out[bs * EMB + tid], acc);
}

extern "C" void kernel_launch(void* const* d_in, const int* in_sizes, int n_in,
                              void* d_out, int out_size, void* d_ws, size_t ws_size,
                              hipStream_t stream) {
    const float* x    = (const float*)d_in[0];
    const float* mask = (const float*)d_in[1];
    const float* W_w  = (const float*)d_in[2];
    const float* W_b  = (const float*)d_in[3];
    const float* U_w  = (const float*)d_in[4];
    const float* U_b  = (const float*)d_in[5];
    const float* v_w  = (const float*)d_in[6];
    const float* v_b  = (const float*)d_in[7];
    const float* m    = (const float*)d_in[8];
    float* out = (float*)d_out;

    float* ws     = (float*)d_ws;
    float* pooled = ws;                          // B*S*FEA
    float* u_buf  = pooled + B * S * FEA;        // NCL*H
    float* w_buf  = u_buf + NCL * H;             // B*S*H

    pool_kernel<<<dim3(FEA / (16 * TPB), B), 256, 0, stream>>>(x, mask, pooled);
    wden_kernel<<<B * S, 256, 0, stream>>>(pooled, mask, W_w, W_b, U_w, U_b, m,
                                           w_buf, u_buf, out);
    egemv_kernel<<<B * S * 4, 256, 0, stream>>>(w_buf, u_buf, v_w, v_b, m, out);
}

// Round 19
// 60.118 us; speedup vs baseline: 1.0335x; 1.0335x over previous
//
#include <hip/hip_runtime.h>
#include <hip/hip_bf16.h>
#include <math.h>

#define B 32
#define S 8
#define FEA 2560
#define T 800
#define NCL 512
#define EMB 256
#define H 8

#define BF 64            // features per block (16 per wave)
#define SEC 128          // k floats per staged section
#define NSEC 6           // full sections (k 0..767); tail 32 via direct-global MFMA
#define MROWB 1664       // bytes per mask row in LDS (1600 data + 64 pad)

typedef __attribute__((ext_vector_type(8))) short bf16x8;
typedef __attribute__((ext_vector_type(4))) float f32x4;

__device__ __forceinline__ short4 cvt_bf16x4(float4 v) {
    union { short4 s4; __hip_bfloat162 h[2]; } u;
    u.h[0] = __float22bfloat162_rn(make_float2(v.x, v.y));
    u.h[1] = __float22bfloat162_rn(make_float2(v.z, v.w));
    return u.s4;
}

// Stage: thread covers rows r*8+(tid>>5), cols [(tid&31)*4, +4) of the 128-float
// section window -> each wave instruction = 8 rows x 512 B contiguous runs.
#define LOAD_SEC(s) {                                                               \
    _Pragma("unroll")                                                               \
    for (int r = 0; r < 8; ++r)                                                     \
        R[r] = *(const float4*)(xb + (size_t)(f0 + r * 8 + (tid >> 5)) * T          \
                                + (s) * SEC + (tid & 31) * 4);                      \
}

#define WRITE_SEC() {                                                               \
    _Pragma("unroll")                                                               \
    for (int r = 0; r < 8; ++r) {                                                   \
        const int row_ = r * 8 + (tid >> 5);                                        \
        *(short4*)(xls + row_ * 256 + (((tid & 31) * 8) ^ ((row_ & 7) << 4)))       \
            = cvt_bf16x4(R[r]);                                                     \
    }                                                                               \
}

// One MFMA step (32 k) of section sec, step st in 0..3.
#define CSTEP(sec, st) {                                                            \
    const bf16x8 bx_ = *(const bf16x8*)(xls + xrow * 256                            \
                          + ((((st) & 3) * 64 + kb16) ^ xswz));                     \
    const bf16x8 am_ = *(const bf16x8*)((const char*)mask_l + mbase                 \
                          + ((((sec) * 4 + (st)) * 64 + kb16) ^ mswz));             \
    acc = __builtin_amdgcn_mfma_f32_16x16x32_bf16(am_, bx_, acc, 0, 0, 0);          \
}

#define CSEC(sec) { CSTEP(sec,0) CSTEP(sec,1) CSTEP(sec,2) CSTEP(sec,3) }

// ---------------- Kernel A: pooled via MFMA; EXACT 1280 blocks = 5/CU, no tail ----------------
__global__ __launch_bounds__(256, 5) void pool_kernel(const float* __restrict__ x,
                                                      const float* __restrict__ mask,
                                                      float* __restrict__ pooled) {
    const int b = blockIdx.y;

    __shared__ short mask_l[S * (MROWB / 2)];   // 13312 B
    __shared__ char  xls[16384];                // single 64-row x 256 B section buffer

    const int tid = threadIdx.x;
    const int f0  = blockIdx.x * BF;
    const float* xb = x + (size_t)b * FEA * T;

    float4 R[8];

    LOAD_SEC(0)

    for (int v = tid; v < S * 200; v += 256) {
        const int s = v / 200, c4 = v % 200;
        const float4 mv = *(const float4*)(mask + ((size_t)(b * S + s)) * T + c4 * 4);
        const int byte = s * MROWB + ((c4 * 8) ^ (s << 4));
        *(short4*)((char*)mask_l + byte) = cvt_bf16x4(mv);
    }

    WRITE_SEC()
    LOAD_SEC(1)
    __syncthreads();

    const int wave = tid >> 6, lane = tid & 63;
    const int kb16 = (lane >> 4) * 16;
    const int xrow = wave * 16 + (lane & 15);
    const int xswz = (xrow & 7) << 4;
    const int srow = lane & 7;
    const int mbase = srow * MROWB;
    const int mswz = srow << 4;

    f32x4 acc = {0.f, 0.f, 0.f, 0.f};

    #pragma unroll 1
    for (int sec = 0; sec < NSEC; ++sec) {
        CSEC(sec)
        __syncthreads();
        if (sec < NSEC - 1) {
            WRITE_SEC()
            if (sec < NSEC - 2) LOAD_SEC(sec + 2)
        }
        __syncthreads();
    }

    {
        const float* xt = xb + (size_t)(f0 + xrow) * T + 768 + (lane >> 4) * 8;
        const float4 t0 = *(const float4*)(xt);
        const float4 t1 = *(const float4*)(xt + 4);
        union { bf16x8 v; short4 s4[2]; } Bx;
        Bx.s4[0] = cvt_bf16x4(t0);
        Bx.s4[1] = cvt_bf16x4(t1);
        const bf16x8 am = *(const bf16x8*)((const char*)mask_l + mbase
                              + ((24 * 64 + kb16) ^ mswz));
        acc = __builtin_amdgcn_mfma_f32_16x16x32_bf16(am, Bx.v, acc, 0, 0, 0);
    }

    if (lane < 32) {
        const int col = lane & 15;
        #pragma unroll
        for (int i = 0; i < 4; ++i) {
            const int sr = (lane >> 4) * 4 + i;
            pooled[(size_t)(b * S + sr) * FEA + f0 + wave * 16 + col] = acc[i];
        }
    }
}

// ---------------- Kernel B1: per (b,s) denom + w, float4 + shfl-reduce (+ u, + zero out) ----------------
__global__ __launch_bounds__(256) void wden_kernel(const float* __restrict__ pooled,
                                                   const float* __restrict__ mask,
                                                   const float* __restrict__ W_w,
                                                   const float* __restrict__ W_b,
                                                   const float* __restrict__ U_w,
                                                   const float* __restrict__ U_b,
                                                   const float* __restrict__ m,
                                                   float* __restrict__ w_out,
                                                   float* __restrict__ u_out,
                                                   float* __restrict__ out) {
    __shared__ float dred[4];
    __shared__ float wred[4][8];
    const int bs  = blockIdx.x;
    const int tid = threadIdx.x;
    const int lane = tid & 63, wave = tid >> 6;

    out[bs * EMB + tid] = 0.f;   // zero for egemv atomics

    // ---- u: clusters 2bs, 2bs+1 (16 dot-256s; 16-lane groups) ----
    {
        const int job = tid >> 4, sub = tid & 15;
        const int cl  = 2 * bs + (job >> 3), h = job & 7;
        float pu = 0.f;
        #pragma unroll 4
        for (int e = sub; e < EMB; e += 16)
            pu += m[cl * EMB + e] * U_w[h * EMB + e];
        #pragma unroll
        for (int off = 8; off > 0; off >>= 1) pu += __shfl_xor(pu, off, 64);
        if (sub == 0) u_out[cl * H + h] = pu + U_b[h];
    }

    // ---- denom: float4 mask loads + wave shfl reduce (1 barrier) ----
    const float4* mk4 = (const float4*)(mask + (size_t)bs * T);   // 200 float4
    float p = 0.f;
    if (tid < 200) {
        const float4 v = mk4[tid];
        p = v.x + v.y + v.z + v.w;
    }
    #pragma unroll
    for (int off = 32; off > 0; off >>= 1) p += __shfl_xor(p, off, 64);
    if (lane == 0) dred[wave] = p;
    __syncthreads();
    const float inv_d = 1.f / (dred[0] + dred[1] + dred[2] + dred[3] + 1e-10f);

    // ---- w[h]: float4 pooled & W_w loads ----
    const float4* p4 = (const float4*)(pooled + (size_t)bs * FEA);
    const float4* W4 = (const float4*)W_w;
    float acc[8];
    #pragma unroll
    for (int h = 0; h < 8; ++h) acc[h] = 0.f;
    #pragma unroll 1
    for (int i = tid; i < FEA / 4; i += 256) {
        float4 xv = p4[i];
        xv.x *= inv_d; xv.y *= inv_d; xv.z *= inv_d; xv.w *= inv_d;
        #pragma unroll
        for (int h = 0; h < 8; ++h) {
            const float4 wv = W4[h * (FEA / 4) + i];
            acc[h] += xv.x * wv.x + xv.y * wv.y + xv.z * wv.z + xv.w * wv.w;
        }
    }
    #pragma unroll
    for (int h = 0; h < 8; ++h) {
        float v = acc[h];
        #pragma unroll
        for (int off = 32; off > 0; off >>= 1) v += __shfl_xor(v, off, 64);
        if (lane == 0) wred[wave][h] = v;
    }
    __syncthreads();
    if (tid < 8)
        w_out[bs * H + tid] = wred[0][tid] + wred[1][tid] + wred[2][tid] + wred[3][tid] + W_b[tid];
}

// ---------------- Kernel B2: fused gate + e = a @ m, n-split x4 ----------------
__global__ __launch_bounds__(256) void egemv_kernel(const float* __restrict__ w_buf,
                                                    const float* __restrict__ u_buf,
                                                    const float* __restrict__ v_w,
                                                    const float* __restrict__ v_b,
                                                    const float* __restrict__ m,
                                                    float* __restrict__ out) {
    __shared__ float a_sh[128];
    const int bs = blockIdx.x >> 2, q = blockIdx.x & 3;
    const int tid = threadIdx.x;
    const int n0 = q * 128;

    if (tid < 128) {
        const int n = n0 + tid;
        float c = v_b[0];
        #pragma unroll
        for (int h = 0; h < 8; ++h)
            c += tanhf(w_buf[bs * H + h] + u_buf[n * H + h]) * v_w[h];
        a_sh[tid] = 1.f / (1.f + expf(-c));
    }
    __syncthreads();

    float acc = 0.f;
    #pragma unroll 8
    for (int j = 0; j < 128; ++j)
        acc += a_sh[j] * m[(n0 + j) * EMB + tid];
    atomicAdd(&out[bs * EMB + tid], acc);
}

extern "C" void kernel_launch(void* const* d_in, const int* in_sizes, int n_in,
                              void* d_out, int out_size, void* d_ws, size_t ws_size,
                              hipStream_t stream) {
    const float* x    = (const float*)d_in[0];
    const float* mask = (const float*)d_in[1];
    const float* W_w  = (const float*)d_in[2];
    const float* W_b  = (const float*)d_in[3];
    const float* U_w  = (const float*)d_in[4];
    const float* U_b  = (const float*)d_in[5];
    const float* v_w  = (const float*)d_in[6];
    const float* v_b  = (const float*)d_in[7];
    const float* m    = (const float*)d_in[8];
    float* out = (float*)d_out;

    float* ws     = (float*)d_ws;
    float* pooled = ws;                          // B*S*FEA
    float* u_buf  = pooled + B * S * FEA;        // NCL*H
    float* w_buf  = u_buf + NCL * H;             // B*S*H

    pool_kernel<<<dim3(FEA / BF, B), 256, 0, stream>>>(x, mask, pooled);
    wden_kernel<<<B * S, 256, 0, stream>>>(pooled, mask, W_w, W_b, U_w, U_b, m,
                                           w_buf, u_buf, out);
    egemv_kernel<<<B * S * 4, 256, 0, stream>>>(w_buf, u_buf, v_w, v_b, m, out);
}